// Round 2
// baseline (2547.492 us; speedup 1.0000x reference)
//
#include <hip/hip_runtime.h>

typedef _Float16 f16_t;
typedef _Float16 f16x4 __attribute__((ext_vector_type(4)));
typedef _Float16 f16x8 __attribute__((ext_vector_type(8)));
typedef float floatx4 __attribute__((ext_vector_type(4)));

#define GLDS16(gptr, lptr) __builtin_amdgcn_global_load_lds( \
    (const __attribute__((address_space(1))) void*)(gptr),   \
    (__attribute__((address_space(3))) void*)(lptr), 16, 0, 0)

#define SBAR()  asm volatile("s_barrier" ::: "memory")
#define LGKM0() do { asm volatile("s_waitcnt lgkmcnt(0)" ::: "memory"); \
                     __builtin_amdgcn_sched_barrier(0); } while (0)

__device__ __forceinline__ float sigmoidf_fast(float x) {
    return 1.f / (1.f + __expf(-x));
}
__device__ __forceinline__ float tanhf_fast(float x) {
    float e = __expf(2.f * x);
    return 1.f - 2.f / (e + 1.f);
}

// gi fragment layout: off = ((g*512 + tM)*128 + tN)*256 + lane*4 + r   (f16)
#define GATE_STRIDE 16777216L   // 512*128*256

// ---------------------------------------------------------------------------
__global__ __launch_bounds__(256)
void cvt_f32_f16(const float* __restrict__ in, f16_t* __restrict__ out, long n)
{
    long i = ((long)blockIdx.x * 256 + threadIdx.x) * 8;
    if (i >= n) return;
    floatx4 a = *(const floatx4*)(in + i);
    floatx4 b = *(const floatx4*)(in + i + 4);
    f16x8 o;
    o[0] = (f16_t)a[0]; o[1] = (f16_t)a[1]; o[2] = (f16_t)a[2]; o[3] = (f16_t)a[3];
    o[4] = (f16_t)b[0]; o[5] = (f16_t)b[1]; o[6] = (f16_t)b[2]; o[7] = (f16_t)b[3];
    *(f16x8*)(out + i) = o;
}

// ---------------------------------------------------------------------------
// gi = encoded @ w_ih^T + b_ih, fragment-tiled output.
// 2-phase double-buffered pipeline (unchanged from R1 — next target).
// ---------------------------------------------------------------------------
__device__ __forceinline__ void stage_gi(const f16_t* __restrict__ A,
                                         const f16_t* __restrict__ W,
                                         f16_t* Asb, f16_t* Wsb,
                                         int m0, int n0, int k0,
                                         int wave, int srow, int skc)
{
    const int K = 2048;
    #pragma unroll
    for (int j = 0; j < 2; ++j) {
        int c = j * 4 + wave;
        int row = c * 16 + srow;
        GLDS16(A + (size_t)(m0 + row) * K + k0 + skc, Asb + c * 512);
    }
    #pragma unroll
    for (int j = 0; j < 2; ++j) {
        int c = j * 4 + wave;
        int row = c * 16 + srow;
        GLDS16(W + (size_t)(n0 + row) * K + k0 + skc, Wsb + c * 512);
    }
}

__global__ __launch_bounds__(256, 2)
void gemm_gi(const f16_t* __restrict__ A,
             const f16_t* __restrict__ W,
             const float* __restrict__ bias,
             f16_t* __restrict__ giF)
{
    __shared__ __align__(16) f16_t smem[2 * 8192];   // 32 KiB
    const int tid  = threadIdx.x;
    const int lane = tid & 63;
    const int wave = tid >> 6;
    const int m0 = blockIdx.x * 128;
    const int n0 = blockIdx.y * 128;
    const int wm = (wave >> 1) * 64;
    const int wn = (wave & 1) * 64;

    floatx4 acc[4][4] = {};

    const int srow = lane >> 2;
    const int skc  = (((lane & 3) ^ ((srow >> 1) & 3))) * 8;
    const int fr = lane & 15;
    const int jq = lane >> 4;
    const int jsw = (jq ^ ((fr >> 1) & 3)) * 8;

    stage_gi(A, W, smem, smem + 4096, m0, n0, 0, wave, srow, skc);
    __syncthreads();

    for (int t = 0; t < 64; ++t) {
        f16_t* As = smem + (t & 1) * 8192;
        f16_t* Ws = As + 4096;
        if (t < 63) {
            f16_t* Asn = smem + ((t + 1) & 1) * 8192;
            stage_gi(A, W, Asn, Asn + 4096, m0, n0, (t + 1) * 32,
                     wave, srow, skc);
        }

        f16x8 a_frag[4], b_frag[4];
        #pragma unroll
        for (int u = 0; u < 4; ++u)
            a_frag[u] = *(const f16x8*)(As + (wm + u * 16 + fr) * 32 + jsw);
        #pragma unroll
        for (int u = 0; u < 4; ++u)
            b_frag[u] = *(const f16x8*)(Ws + (wn + u * 16 + fr) * 32 + jsw);
        #pragma unroll
        for (int tm = 0; tm < 4; ++tm)
            #pragma unroll
            for (int tn = 0; tn < 4; ++tn)
                acc[tm][tn] = __builtin_amdgcn_mfma_f32_16x16x32_f16(
                    a_frag[tm], b_frag[tn], acc[tm][tn], 0, 0, 0);
        __syncthreads();
    }

    const int g   = n0 >> 11;
    const int tNb = ((n0 & 2047) >> 4) + (wn >> 4);
    #pragma unroll
    for (int tm = 0; tm < 4; ++tm) {
        int tM = (m0 + wm + tm * 16) >> 4;
        #pragma unroll
        for (int tn = 0; tn < 4; ++tn) {
            int tN = tNb + tn;
            int n  = n0 + wn + tn * 16 + fr;
            float b = bias[n];
            f16x4 v;
            #pragma unroll
            for (int r = 0; r < 4; ++r) v[r] = (f16_t)(acc[tm][tn][r] + b);
            *(f16x4*)(giF + ((size_t)(g * 512 + tM) * 128 + tN) * 256 + lane * 4) = v;
        }
    }
}

// ---------------------------------------------------------------------------
// Iteration 1 (h0=0): gh = b_hh only.
// ---------------------------------------------------------------------------
__global__ __launch_bounds__(256)
void gru_init(const f16_t* __restrict__ giF,
              const float* __restrict__ bhh,
              f16_t* __restrict__ h16)
{
    const int H = 2048;
    __shared__ __align__(16) f16_t hp[128 * 72];
    const int tid  = threadIdx.x;
    const int lane = tid & 63;
    const int wave = tid >> 6;
    const int m0 = blockIdx.x * 128;
    const int n0 = blockIdx.y * 64;
    const int wm = (wave >> 1) * 64;
    const int wn = (wave & 1) * 32;
    const int colL = lane & 15;
    const int rq = (lane >> 4) * 4;

    #pragma unroll
    for (int tm = 0; tm < 4; ++tm) {
        int tM = (m0 + wm + tm * 16) >> 4;
        #pragma unroll
        for (int tn = 0; tn < 2; ++tn) {
            int tN = ((n0 + wn) >> 4) + tn;
            size_t base = ((size_t)tM * 128 + tN) * 256 + lane * 4;
            f16x4 g_r = *(const f16x4*)(giF + base);
            f16x4 g_z = *(const f16x4*)(giF + base + GATE_STRIDE);
            f16x4 g_n = *(const f16x4*)(giF + base + 2 * GATE_STRIDE);
            int n = n0 + wn + tn * 16 + colL;
            float br = bhh[n], bz = bhh[H + n], bn = bhh[2 * H + n];
            #pragma unroll
            for (int r = 0; r < 4; ++r) {
                float rr = sigmoidf_fast((float)g_r[r] + br);
                float zz = sigmoidf_fast((float)g_z[r] + bz);
                float nn = tanhf_fast((float)g_n[r] + rr * bn);
                float h = (1.f - zz) * nn;
                hp[(wm + tm * 16 + rq + r) * 72 + wn + tn * 16 + colL] = (f16_t)h;
            }
        }
    }
    __syncthreads();
    #pragma unroll
    for (int i = 0; i < 4; ++i) {
        int r2 = i * 32 + (tid >> 3);
        int ch = tid & 7;
        f16x8 v = *(const f16x8*)(hp + r2 * 72 + ch * 8);
        *(f16x8*)(h16 + (size_t)(m0 + r2) * H + n0 + ch * 8) = v;
    }
}

// ---------------------------------------------------------------------------
// Fused gh-GEMM (3 gates) + GRU update.
// R6: 8-wave (512-thread) BM=256 block, BK=64; 3-phase/K-tile schedule with
// counted vmcnt (T3+T4) + setprio around 16-MFMA clusters (T5).
//   phase 0: ds a(s0) + b(g0,s0),(g1,s0); issue W(t+1); bar; lgkm0;
//            MFMA g0/g1(s0); bar
//   phase 1: ds a(s1) + b(g2,s0),(g0,s1); bar; lgkm0; MFMA g2(s0)/g0(s1); bar
//   phase 2: ds b(g1,s1),(g2,s1); issue A(t+2) (into As — reads done @p1);
//            bar; lgkm0; MFMA g1/g2(s1); bar
//   publish: s_waitcnt vmcnt(4)  [A(t+2) stays in flight]; bar
// LDS 112 KiB (A 2x32 KiB, W 2x24 KiB) -> 1 block/CU, 2 waves/SIMD.
// hold(h_prev) captured from As at k0 == n0. XCD-swizzled grid: 3 MB w_hh
// slice per XCD stays L2-resident.
// ---------------------------------------------------------------------------
__device__ __forceinline__ void stage_A8(const f16_t* __restrict__ hin,
                                         f16_t* Asb, int m0, int kk,
                                         int wave, int srow8, int sgk)
{
    const int K = 2048;
    #pragma unroll
    for (int j = 0; j < 4; ++j) {
        int c = j * 8 + wave;            // 32 chunks of 8 rows x 64 f16
        int row = c * 8 + srow8;
        GLDS16(hin + (size_t)(m0 + row) * K + kk + sgk, Asb + c * 512);
    }
}
__device__ __forceinline__ void stage_W8(const f16_t* __restrict__ Wh,
                                         f16_t* Wsb, int n0, int kk,
                                         int wave, int srow8, int sgk)
{
    const int K = 2048, H = 2048;
    #pragma unroll
    for (int j = 0; j < 3; ++j) {
        int c = j * 8 + wave;            // 24 chunks (3 gates x 8)
        int g = c >> 3;
        int cw = c & 7;
        int row = cw * 8 + srow8;
        GLDS16(Wh + (size_t)(g * H + n0 + row) * K + kk + sgk, Wsb + c * 512);
    }
}

__global__ __launch_bounds__(512, 1)
void gru_step(const f16_t* __restrict__ Wh,
              const float* __restrict__ bhh,
              const f16_t* __restrict__ giF,
              const f16_t* __restrict__ hin,
              f16_t* __restrict__ hout,
              float* __restrict__ out32)
{
    const int H = 2048;
    // A bufs: 2 x 256x64 f16 = 64 KiB; W bufs: 2 x 3x64x64 f16 = 48 KiB
    __shared__ __align__(16) f16_t smem[2 * 16384 + 2 * 12288];  // 112 KiB
    f16_t* smA = smem;
    f16_t* smW = smem + 32768;
    const int tid  = threadIdx.x;
    const int lane = tid & 63;
    const int wave = tid >> 6;      // 0..7

    // XCD-aware decomposition of 1024 blocks
    const int bid   = blockIdx.x;
    const int xcd   = bid & 7;
    const int rblk  = bid >> 3;                   // 0..127
    const int m0 = (rblk >> 2) * 256;             // 32 m-tiles
    const int n0 = (xcd * 4 + (rblk & 3)) * 64;   // 32 n-tiles

    const int wm = (wave >> 1) * 64;              // 0,64,128,192
    const int wn = (wave & 1) * 32;

    floatx4 acc[3][4][2] = {};

    // staging: 1 KiB chunk = 8 rows x 64 f16; lane -> row lane>>3, slot lane&7
    const int srow8 = lane >> 3;
    const int sgk   = ((lane & 7) ^ srow8) * 8;   // swizzled global chunk
    const int fr = lane & 15;
    const int jq = lane >> 4;                     // 0..3
    const int rq = (lane >> 4) * 4;

    f16x4 hold16[4][2];   // h_prev captured from LDS

#define LOADA(dst, s) do {                                               \
    _Pragma("unroll")                                                    \
    for (int u = 0; u < 4; ++u) {                                        \
        int row = wm + u * 16 + fr;                                      \
        int slot = ((s) * 4 + jq) ^ (row & 7);                           \
        dst[u] = *(const f16x8*)(As + row * 64 + slot * 8);              \
    } } while (0)
#define LOADB(dst, g, s) do {                                            \
    _Pragma("unroll")                                                    \
    for (int tn = 0; tn < 2; ++tn) {                                     \
        int row_w = wn + tn * 16 + fr;                                   \
        int slot = ((s) * 4 + jq) ^ (row_w & 7);                         \
        dst[tn] = *(const f16x8*)(Ws + (g) * 4096 + row_w * 64 + slot * 8); \
    } } while (0)
#define MFMA8(g, af, bf) do {                                            \
    _Pragma("unroll")                                                    \
    for (int tn = 0; tn < 2; ++tn)                                       \
        _Pragma("unroll")                                                \
        for (int tm = 0; tm < 4; ++tm)                                   \
            acc[g][tm][tn] = __builtin_amdgcn_mfma_f32_16x16x32_f16(     \
                af[tm], bf[tn], acc[g][tm][tn], 0, 0, 0);                \
    } while (0)

    // prologue: A(0), W(0), A(1); leave A(1) in flight
    stage_A8(hin, smA, m0, 0, wave, srow8, sgk);
    stage_W8(Wh, smW, n0, 0, wave, srow8, sgk);
    stage_A8(hin, smA + 16384, m0, 64, wave, srow8, sgk);
    asm volatile("s_waitcnt vmcnt(4)" ::: "memory");
    SBAR();

    for (int t = 0; t < 32; ++t) {
        const int k0 = t << 6;
        f16_t* As = smA + (t & 1) * 16384;
        f16_t* Ws = smW + (t & 1) * 12288;
        f16_t* Wn = smW + ((t + 1) & 1) * 12288;

        if (k0 == n0) {   // wave-uniform, once: capture h_prev from As
            #pragma unroll
            for (int tm = 0; tm < 4; ++tm) {
                #pragma unroll
                for (int tn = 0; tn < 2; ++tn) {
                    #pragma unroll
                    for (int r = 0; r < 4; ++r) {
                        int row_a = wm + tm * 16 + rq + r;
                        int kloc  = wn + tn * 16 + fr;
                        int slot  = (kloc >> 3) ^ (row_a & 7);
                        hold16[tm][tn][r] =
                            As[row_a * 64 + slot * 8 + (kloc & 7)];
                    }
                }
            }
        }

        f16x8 aS0[4], aS1[4], bA[2], bB[2];

        // ---- phase 0: MFMA (g0,s0) + (g1,s0) ----
        LOADA(aS0, 0);
        LOADB(bA, 0, 0);
        LOADB(bB, 1, 0);
        if (t < 31) stage_W8(Wh, Wn, n0, k0 + 64, wave, srow8, sgk);
        SBAR();
        LGKM0();
        __builtin_amdgcn_s_setprio(1);
        MFMA8(0, aS0, bA);
        MFMA8(1, aS0, bB);
        __builtin_amdgcn_s_setprio(0);
        SBAR();

        // ---- phase 1: MFMA (g2,s0) + (g0,s1) ----
        LOADA(aS1, 1);
        LOADB(bA, 2, 0);
        LOADB(bB, 0, 1);
        SBAR();
        LGKM0();
        __builtin_amdgcn_s_setprio(1);
        MFMA8(2, aS0, bA);
        MFMA8(0, aS1, bB);
        __builtin_amdgcn_s_setprio(0);
        SBAR();

        // ---- phase 2: MFMA (g1,s1) + (g2,s1) ----
        LOADB(bA, 1, 1);
        LOADB(bB, 2, 1);
        if (t < 30) stage_A8(hin, As, m0, k0 + 128, wave, srow8, sgk);
        SBAR();
        LGKM0();
        __builtin_amdgcn_s_setprio(1);
        MFMA8(1, aS1, bA);
        MFMA8(2, aS1, bB);
        __builtin_amdgcn_s_setprio(0);
        SBAR();

        // ---- publish next tile ----
        if (t < 31) {
            if (t < 30) asm volatile("s_waitcnt vmcnt(4)" ::: "memory");
            else        asm volatile("s_waitcnt vmcnt(0)" ::: "memory");
            SBAR();
        }
    }

    // epilogue
    f16x4 hv[4][2];
    #pragma unroll
    for (int tm = 0; tm < 4; ++tm) {
        int tM = (m0 + wm + tm * 16) >> 4;
        #pragma unroll
        for (int tn = 0; tn < 2; ++tn) {
            int tN = ((n0 + wn) >> 4) + tn;
            size_t base = ((size_t)tM * 128 + tN) * 256 + lane * 4;
            f16x4 g_r = *(const f16x4*)(giF + base);
            f16x4 g_z = *(const f16x4*)(giF + base + GATE_STRIDE);
            f16x4 g_n = *(const f16x4*)(giF + base + 2 * GATE_STRIDE);
            int n = n0 + wn + tn * 16 + fr;
            float br = bhh[n], bz = bhh[H + n], bn = bhh[2 * H + n];
            #pragma unroll
            for (int r = 0; r < 4; ++r) {
                int m = m0 + wm + tm * 16 + rq + r;
                float rr = sigmoidf_fast((float)g_r[r] + acc[0][tm][tn][r] + br);
                float zz = sigmoidf_fast((float)g_z[r] + acc[1][tm][tn][r] + bz);
                float nn = tanhf_fast((float)g_n[r] +
                                      rr * (acc[2][tm][tn][r] + bn));
                float hold = (float)hold16[tm][tn][r];
                float hnew = (1.f - zz) * nn + zz * hold;
                hv[tm][tn][r] = (f16_t)hnew;
                if (out32) out32[(size_t)m * H + n] = hnew;
            }
        }
    }

    if (!out32) {
        f16_t* hp = smem;   // 256*72 f16 = 36 KiB, fits; loop's final SBAR
                            // aligned all waves past their last LDS reads
        #pragma unroll
        for (int tm = 0; tm < 4; ++tm)
            #pragma unroll
            for (int tn = 0; tn < 2; ++tn)
                #pragma unroll
                for (int r = 0; r < 4; ++r)
                    hp[(wm + tm * 16 + rq + r) * 72 + wn + tn * 16 + fr] =
                        hv[tm][tn][r];
        __syncthreads();
        #pragma unroll
        for (int i = 0; i < 4; ++i) {
            int r2 = i * 64 + (tid >> 3);
            int ch = tid & 7;
            f16x8 v = *(const f16x8*)(hp + r2 * 72 + ch * 8);
            *(f16x8*)(hout + (size_t)(m0 + r2) * H + n0 + ch * 8) = v;
        }
    }
#undef LOADA
#undef LOADB
#undef MFMA8
}

extern "C" void kernel_launch(void* const* d_in, const int* in_sizes, int n_in,
                              void* d_out, int out_size, void* d_ws, size_t ws_size,
                              hipStream_t stream) {
    const float* x    = (const float*)d_in[0];
    const float* w_ih = (const float*)d_in[1];
    const float* w_hh = (const float*)d_in[2];
    const float* b_ih = (const float*)d_in[3];
    const float* b_hh = (const float*)d_in[4];
    float* out = (float*)d_out;

    char* ws = (char*)d_ws;
    f16_t* xh    = (f16_t*)(ws);
    f16_t* wih_h = (f16_t*)(ws + 33554432);
    f16_t* whh_h = (f16_t*)(ws + 33554432 + 25165824);
    f16_t* gi    = (f16_t*)(ws + 33554432 + 2 * 25165824);
    f16_t* h16a  = (f16_t*)(ws + 33554432 + 2 * 25165824 + 100663296);
    f16_t* h16b  = (f16_t*)(ws + 33554432 + 2 * 25165824 + 100663296 + 33554432);

    cvt_f32_f16<<<dim3(8192), 256, 0, stream>>>(x, xh, 16777216L);
    cvt_f32_f16<<<dim3(6144), 256, 0, stream>>>(w_ih, wih_h, 12582912L);
    cvt_f32_f16<<<dim3(6144), 256, 0, stream>>>(w_hh, whh_h, 12582912L);

    gemm_gi<<<dim3(64, 48), 256, 0, stream>>>(xh, wih_h, b_ih, gi);
    gru_init<<<dim3(64, 32), 256, 0, stream>>>(gi, b_hh, h16a);

    f16_t* hin = h16a; f16_t* hout = h16b;
    for (int it = 2; it <= 10; ++it) {
        float* o32 = (it == 10) ? out : nullptr;
        gru_step<<<dim3(1024), 512, 0, stream>>>(whh_h, b_hh, gi,
                                                 hin, hout, o32);
        f16_t* t = hin; hin = hout; hout = t;
    }
}

// Round 3
// 2314.211 us; speedup vs baseline: 1.1008x; 1.1008x over previous
//
#include <hip/hip_runtime.h>

typedef _Float16 f16_t;
typedef _Float16 f16x4 __attribute__((ext_vector_type(4)));
typedef _Float16 f16x8 __attribute__((ext_vector_type(8)));
typedef float floatx4 __attribute__((ext_vector_type(4)));

#define GLDS16(gptr, lptr) __builtin_amdgcn_global_load_lds( \
    (const __attribute__((address_space(1))) void*)(gptr),   \
    (__attribute__((address_space(3))) void*)(lptr), 16, 0, 0)

__device__ __forceinline__ float sigmoidf_fast(float x) {
    return 1.f / (1.f + __expf(-x));
}
__device__ __forceinline__ float tanhf_fast(float x) {
    float e = __expf(2.f * x);
    return 1.f - 2.f / (e + 1.f);
}

// gi fragment layout: off = ((g*512 + tM)*128 + tN)*256 + lane*4 + r   (f16)
#define GATE_STRIDE 16777216L   // 512*128*256

// ---------------------------------------------------------------------------
__global__ __launch_bounds__(256)
void cvt_f32_f16(const float* __restrict__ in, f16_t* __restrict__ out, long n)
{
    long i = ((long)blockIdx.x * 256 + threadIdx.x) * 8;
    if (i >= n) return;
    floatx4 a = *(const floatx4*)(in + i);
    floatx4 b = *(const floatx4*)(in + i + 4);
    f16x8 o;
    o[0] = (f16_t)a[0]; o[1] = (f16_t)a[1]; o[2] = (f16_t)a[2]; o[3] = (f16_t)a[3];
    o[4] = (f16_t)b[0]; o[5] = (f16_t)b[1]; o[6] = (f16_t)b[2]; o[7] = (f16_t)b[3];
    *(f16x8*)(out + i) = o;
}

// ---------------------------------------------------------------------------
// Shared staging helper: A-tile 128x64 (16 chunks of 8 rows x 64 f16) and
// W-tile 3 gates x 64 rows x 64 (24 chunks), 1 KiB chunks, 8-slot XOR
// swizzle baked into the per-lane GLOBAL address (LDS dest stays linear).
// ---------------------------------------------------------------------------
__device__ __forceinline__ void stage_AW(const f16_t* __restrict__ Asrc,
                                         const f16_t* __restrict__ Wsrc,
                                         f16_t* Asb, f16_t* Wsb,
                                         int m0, int n0, int kk,
                                         int wave, int srow8, int sgk)
{
    const int K = 2048, H = 2048;
    // A: 16 chunks, 4/wave
    #pragma unroll
    for (int j = 0; j < 4; ++j) {
        int c = j * 4 + wave;
        int row = c * 8 + srow8;
        GLDS16(Asrc + (size_t)(m0 + row) * K + kk + sgk, Asb + c * 512);
    }
    // W: 24 chunks (3 gates x 8), 6/wave
    #pragma unroll
    for (int j = 0; j < 6; ++j) {
        int c = j * 4 + wave;
        int g = c >> 3;
        int cw = c & 7;
        int row = cw * 8 + srow8;
        GLDS16(Wsrc + (size_t)(g * H + n0 + row) * K + kk + sgk,
               Wsb + c * 512);
    }
}

// ---------------------------------------------------------------------------
// gi = encoded @ w_ih^T + b_ih, fragment-tiled output.
// R7: clone of the PROVEN gru_step structure (BM=128, BN=64 x 3 gates fused,
// BK=64, 2-phase double-buffer, stage t+1 BEFORE compute of t, one
// __syncthreads per K-step, XCD-swizzled 2048-block grid so each XCD's
// 3.1 MB w_ih slice stays L2-resident). Epilogue: bias add + fragment write.
// ---------------------------------------------------------------------------
__global__ __launch_bounds__(256, 2)
void gemm_gi(const f16_t* __restrict__ A,
             const f16_t* __restrict__ W,
             const float* __restrict__ bias,
             f16_t* __restrict__ giF)
{
    const int H = 2048;
    // per-buffer tile: As 128x64 (8192 f16) + Wsm 3x64x64 (12288 f16) = 40 KiB
    __shared__ __align__(16) f16_t smem[2 * 20480];  // 80 KiB
    const int tid  = threadIdx.x;
    const int lane = tid & 63;
    const int wave = tid >> 6;

    // XCD-aware decomposition of 2048 blocks
    const int bid   = blockIdx.x;
    const int xcd   = bid & 7;
    const int rblk  = bid >> 3;           // 0..255
    const int m0 = (rblk >> 2) * 128;     // 64 m-tiles
    const int n0 = (xcd * 4 + (rblk & 3)) * 64;   // 32 n-tiles (per gate)

    const int wm = (wave >> 1) * 64;
    const int wn = (wave & 1) * 32;

    floatx4 acc[3][4][2] = {};

    const int srow8 = lane >> 3;
    const int sgk   = ((lane & 7) ^ srow8) * 8;
    const int fr = lane & 15;
    const int jq = lane >> 4;
    const int rq = (lane >> 4) * 4;

    stage_AW(A, W, smem, smem + 8192, m0, n0, 0, wave, srow8, sgk);
    __syncthreads();

    for (int t = 0; t < 32; ++t) {
        f16_t* As  = smem + (t & 1) * 20480;
        f16_t* Wsm = As + 8192;
        if (t < 31) {
            f16_t* Asn = smem + ((t + 1) & 1) * 20480;
            stage_AW(A, W, Asn, Asn + 8192, m0, n0, (t + 1) * 64,
                     wave, srow8, sgk);
        }

        #pragma unroll
        for (int ksub = 0; ksub < 2; ++ksub) {
            f16x8 a_frag[4];
            #pragma unroll
            for (int u = 0; u < 4; ++u) {
                int row = wm + u * 16 + fr;
                int slot = (ksub * 4 + jq) ^ (row & 7);
                a_frag[u] = *(const f16x8*)(As + row * 64 + slot * 8);
            }
            #pragma unroll
            for (int g = 0; g < 3; ++g) {
                #pragma unroll
                for (int tn = 0; tn < 2; ++tn) {
                    int row_w = wn + tn * 16 + fr;
                    int slot = (ksub * 4 + jq) ^ (row_w & 7);
                    f16x8 b_frag = *(const f16x8*)(Wsm + g * 4096 +
                                                   row_w * 64 + slot * 8);
                    #pragma unroll
                    for (int tm = 0; tm < 4; ++tm)
                        acc[g][tm][tn] = __builtin_amdgcn_mfma_f32_16x16x32_f16(
                            a_frag[tm], b_frag, acc[g][tm][tn], 0, 0, 0);
                }
            }
        }
        __syncthreads();
    }

    // epilogue: bias + fragment-tiled store (3 gates)
    #pragma unroll
    for (int tm = 0; tm < 4; ++tm) {
        int tM = (m0 + wm + tm * 16) >> 4;
        #pragma unroll
        for (int tn = 0; tn < 2; ++tn) {
            int tN = ((n0 + wn) >> 4) + tn;
            int n  = n0 + wn + tn * 16 + fr;
            #pragma unroll
            for (int g = 0; g < 3; ++g) {
                float b = bias[g * H + n];
                f16x4 v;
                #pragma unroll
                for (int r = 0; r < 4; ++r) v[r] = (f16_t)(acc[g][tm][tn][r] + b);
                *(f16x4*)(giF + ((size_t)(g * 512 + tM) * 128 + tN) * 256 +
                          lane * 4) = v;
            }
        }
    }
}

// ---------------------------------------------------------------------------
// Iteration 1 (h0=0): gh = b_hh only.
// ---------------------------------------------------------------------------
__global__ __launch_bounds__(256)
void gru_init(const f16_t* __restrict__ giF,
              const float* __restrict__ bhh,
              f16_t* __restrict__ h16)
{
    const int H = 2048;
    __shared__ __align__(16) f16_t hp[128 * 72];
    const int tid  = threadIdx.x;
    const int lane = tid & 63;
    const int wave = tid >> 6;
    const int m0 = blockIdx.x * 128;
    const int n0 = blockIdx.y * 64;
    const int wm = (wave >> 1) * 64;
    const int wn = (wave & 1) * 32;
    const int colL = lane & 15;
    const int rq = (lane >> 4) * 4;

    #pragma unroll
    for (int tm = 0; tm < 4; ++tm) {
        int tM = (m0 + wm + tm * 16) >> 4;
        #pragma unroll
        for (int tn = 0; tn < 2; ++tn) {
            int tN = ((n0 + wn) >> 4) + tn;
            size_t base = ((size_t)tM * 128 + tN) * 256 + lane * 4;
            f16x4 g_r = *(const f16x4*)(giF + base);
            f16x4 g_z = *(const f16x4*)(giF + base + GATE_STRIDE);
            f16x4 g_n = *(const f16x4*)(giF + base + 2 * GATE_STRIDE);
            int n = n0 + wn + tn * 16 + colL;
            float br = bhh[n], bz = bhh[H + n], bn = bhh[2 * H + n];
            #pragma unroll
            for (int r = 0; r < 4; ++r) {
                float rr = sigmoidf_fast((float)g_r[r] + br);
                float zz = sigmoidf_fast((float)g_z[r] + bz);
                float nn = tanhf_fast((float)g_n[r] + rr * bn);
                float h = (1.f - zz) * nn;
                hp[(wm + tm * 16 + rq + r) * 72 + wn + tn * 16 + colL] = (f16_t)h;
            }
        }
    }
    __syncthreads();
    #pragma unroll
    for (int i = 0; i < 4; ++i) {
        int r2 = i * 32 + (tid >> 3);
        int ch = tid & 7;
        f16x8 v = *(const f16x8*)(hp + r2 * 72 + ch * 8);
        *(f16x8*)(h16 + (size_t)(m0 + r2) * H + n0 + ch * 8) = v;
    }
}

// ---------------------------------------------------------------------------
// Fused gh-GEMM (3 gates) + GRU update. BM=128, BN=64, BK=64.
// R1-PROVEN version (restored verbatim): 2-phase double-buffered pipeline —
// stage tile t+1 BEFORE compute of tile t; single __syncthreads per K-step.
// LDS 80 KiB, 2 blocks/CU = 160 KiB exact fit (cross-block overlap is the
// latency-hiding mechanism — do not collapse to 1 block/CU, see R2 failure).
// hold(h_prev) captured from the As tile at k0 == n0 (no global re-read).
// XCD-swizzled 1D grid: each XCD sees 4 n-tiles (3.1 MB w_hh slice in L2).
// ---------------------------------------------------------------------------
__global__ __launch_bounds__(256, 2)
void gru_step(const f16_t* __restrict__ Wh,
              const float* __restrict__ bhh,
              const f16_t* __restrict__ giF,
              const f16_t* __restrict__ hin,
              f16_t* __restrict__ hout,
              float* __restrict__ out32)
{
    const int H = 2048;
    __shared__ __align__(16) f16_t smem[2 * 20480];  // 80 KiB
    const int tid  = threadIdx.x;
    const int lane = tid & 63;
    const int wave = tid >> 6;

    const int bid   = blockIdx.x;
    const int xcd   = bid & 7;
    const int rblk  = bid >> 3;           // 0..255
    const int m0 = (rblk >> 2) * 128;     // 64 m-tiles
    const int n0 = (xcd * 4 + (rblk & 3)) * 64;   // 32 n-tiles

    const int wm = (wave >> 1) * 64;
    const int wn = (wave & 1) * 32;

    floatx4 acc[3][4][2] = {};

    const int srow8 = lane >> 3;
    const int sgk   = ((lane & 7) ^ srow8) * 8;
    const int fr = lane & 15;
    const int jq = lane >> 4;
    const int rq = (lane >> 4) * 4;

    f16x4 hold16[4][2];   // h_prev captured from LDS

    stage_AW(hin, Wh, smem, smem + 8192, m0, n0, 0, wave, srow8, sgk);
    __syncthreads();

    for (int t = 0; t < 32; ++t) {
        const int k0 = t * 64;
        f16_t* As  = smem + (t & 1) * 20480;
        f16_t* Wsm = As + 8192;
        if (t < 31) {
            f16_t* Asn = smem + ((t + 1) & 1) * 20480;
            stage_AW(hin, Wh, Asn, Asn + 8192, m0, n0, k0 + 64,
                     wave, srow8, sgk);
        }

        if (k0 == n0) {   // wave-uniform, once: capture h_prev from As
            #pragma unroll
            for (int tm = 0; tm < 4; ++tm) {
                #pragma unroll
                for (int tn = 0; tn < 2; ++tn) {
                    #pragma unroll
                    for (int r = 0; r < 4; ++r) {
                        int row_a = wm + tm * 16 + rq + r;
                        int kloc  = wn + tn * 16 + fr;
                        int slot  = (kloc >> 3) ^ (row_a & 7);
                        hold16[tm][tn][r] =
                            As[row_a * 64 + slot * 8 + (kloc & 7)];
                    }
                }
            }
        }

        #pragma unroll
        for (int ksub = 0; ksub < 2; ++ksub) {
            f16x8 a_frag[4];
            #pragma unroll
            for (int u = 0; u < 4; ++u) {
                int row = wm + u * 16 + fr;
                int slot = (ksub * 4 + jq) ^ (row & 7);
                a_frag[u] = *(const f16x8*)(As + row * 64 + slot * 8);
            }
            #pragma unroll
            for (int g = 0; g < 3; ++g) {
                #pragma unroll
                for (int tn = 0; tn < 2; ++tn) {
                    int row_w = wn + tn * 16 + fr;
                    int slot = (ksub * 4 + jq) ^ (row_w & 7);
                    f16x8 b_frag = *(const f16x8*)(Wsm + g * 4096 +
                                                   row_w * 64 + slot * 8);
                    #pragma unroll
                    for (int tm = 0; tm < 4; ++tm)
                        acc[g][tm][tn] = __builtin_amdgcn_mfma_f32_16x16x32_f16(
                            a_frag[tm], b_frag, acc[g][tm][tn], 0, 0, 0);
                }
            }
        }
        __syncthreads();
    }

    // epilogue
    f16x4 hv[4][2];
    #pragma unroll
    for (int tm = 0; tm < 4; ++tm) {
        int tM = (m0 + wm + tm * 16) >> 4;
        #pragma unroll
        for (int tn = 0; tn < 2; ++tn) {
            int tN = ((n0 + wn) >> 4) + tn;
            size_t base = ((size_t)tM * 128 + tN) * 256 + lane * 4;
            f16x4 g_r = *(const f16x4*)(giF + base);
            f16x4 g_z = *(const f16x4*)(giF + base + GATE_STRIDE);
            f16x4 g_n = *(const f16x4*)(giF + base + 2 * GATE_STRIDE);
            int n = n0 + wn + tn * 16 + fr;
            float br = bhh[n], bz = bhh[H + n], bn = bhh[2 * H + n];
            #pragma unroll
            for (int r = 0; r < 4; ++r) {
                int m = m0 + wm + tm * 16 + rq + r;
                float rr = sigmoidf_fast((float)g_r[r] + acc[0][tm][tn][r] + br);
                float zz = sigmoidf_fast((float)g_z[r] + acc[1][tm][tn][r] + bz);
                float nn = tanhf_fast((float)g_n[r] +
                                      rr * (acc[2][tm][tn][r] + bn));
                float hold = (float)hold16[tm][tn][r];
                float hnew = (1.f - zz) * nn + zz * hold;
                hv[tm][tn][r] = (f16_t)hnew;
                if (out32) out32[(size_t)m * H + n] = hnew;
            }
        }
    }

    if (!out32) {
        f16_t* hp = smem;   // reuse buf0 region; guarded by last barrier
        #pragma unroll
        for (int tm = 0; tm < 4; ++tm)
            #pragma unroll
            for (int tn = 0; tn < 2; ++tn)
                #pragma unroll
                for (int r = 0; r < 4; ++r)
                    hp[(wm + tm * 16 + rq + r) * 72 + wn + tn * 16 + fr] =
                        hv[tm][tn][r];
        __syncthreads();
        #pragma unroll
        for (int i = 0; i < 4; ++i) {
            int r2 = i * 32 + (tid >> 3);
            int ch = tid & 7;
            f16x8 v = *(const f16x8*)(hp + r2 * 72 + ch * 8);
            *(f16x8*)(hout + (size_t)(m0 + r2) * H + n0 + ch * 8) = v;
        }
    }
}

extern "C" void kernel_launch(void* const* d_in, const int* in_sizes, int n_in,
                              void* d_out, int out_size, void* d_ws, size_t ws_size,
                              hipStream_t stream) {
    const float* x    = (const float*)d_in[0];
    const float* w_ih = (const float*)d_in[1];
    const float* w_hh = (const float*)d_in[2];
    const float* b_ih = (const float*)d_in[3];
    const float* b_hh = (const float*)d_in[4];
    float* out = (float*)d_out;

    char* ws = (char*)d_ws;
    f16_t* xh    = (f16_t*)(ws);
    f16_t* wih_h = (f16_t*)(ws + 33554432);
    f16_t* whh_h = (f16_t*)(ws + 33554432 + 25165824);
    f16_t* gi    = (f16_t*)(ws + 33554432 + 2 * 25165824);
    f16_t* h16a  = (f16_t*)(ws + 33554432 + 2 * 25165824 + 100663296);
    f16_t* h16b  = (f16_t*)(ws + 33554432 + 2 * 25165824 + 100663296 + 33554432);

    cvt_f32_f16<<<dim3(8192), 256, 0, stream>>>(x, xh, 16777216L);
    cvt_f32_f16<<<dim3(6144), 256, 0, stream>>>(w_ih, wih_h, 12582912L);
    cvt_f32_f16<<<dim3(6144), 256, 0, stream>>>(w_hh, whh_h, 12582912L);

    gemm_gi<<<dim3(2048), 256, 0, stream>>>(xh, wih_h, b_ih, gi);
    gru_init<<<dim3(64, 32), 256, 0, stream>>>(gi, b_hh, h16a);

    f16_t* hin = h16a; f16_t* hout = h16b;
    for (int it = 2; it <= 10; ++it) {
        float* o32 = (it == 10) ? out : nullptr;
        gru_step<<<dim3(2048), 256, 0, stream>>>(whh_h, b_hh, gi,
                                                 hin, hout, o32);
        f16_t* t = hin; hin = hout; hout = t;
    }
}